// Round 3
// baseline (327.133 us; speedup 1.0000x reference)
//
#include <hip/hip_runtime.h>

// Problem constants (fixed by the reference)
#define B_   2
#define DZ   41
#define HY   400
#define WX   352
#define NVOX 40000
#define PD   43      // DZ+2
#define PH   402     // HY+2
#define PW   354     // WX+2
#define DO_  21
#define HO_  200
#define WO_  176
#define C1   128
#define GRID_CELLS (B_*PD*PH*PW)        // 12,238,488
#define OUT_POS    (B_*DO_*HO_*WO_)     // 1,478,400
#define OUT_BYTES  ((size_t)OUT_POS * 32 * sizeof(float))   // 189,235,200 B

// Journal:
// R4: 306.5. R5 exact-size memset: 306.0 (NO-OP -> out_size was already floats;
//     739,200KB fills are HARNESS poison of a ~757MB alloc, likely partly inside
//     the timed window ~113us floor).
// R6: compacted taps + 4-chain subm: 316.1 (NEUTRAL -> subm1 never dominated;
//     old 182us note was the GATHER downsample conv, since replaced by scatter).
// R7: budget est: poison 113 + memsets 33 + nbr 20 + subm1 35 + subm2 15 +
//     scatter 40 + relu 35. Attack relu (flag + dense flag-scan relu, no tap
//     re-derivation, no duplicate R/W) and subm1 (wave-per-voxel, transposed
//     W1t[k][d][c] so weights load as float4; shfl reduce). Predict ~260us.

// ---- build padded dense grid of (voxel id + 1), 0 = empty ----
__global__ void k_build(const int* __restrict__ coors, unsigned short* __restrict__ grid) {
    int n = blockIdx.x * blockDim.x + threadIdx.x;
    if (n >= NVOX) return;
    int b = coors[4*n+0], z = coors[4*n+1], y = coors[4*n+2], x = coors[4*n+3];
    grid[((b*PD + z+1)*PH + y+1)*PW + x+1] = (unsigned short)(n + 1);
}

// ---- transpose W1[k][c][d] -> W1t[k][d][c] (27*128*16 = 55296 floats) ----
__global__ void k_wtrans(const float* __restrict__ W1, float* __restrict__ W1t) {
    int i = blockIdx.x * blockDim.x + threadIdx.x;
    if (i >= 27*C1*16) return;
    int k = i / (C1*16), r = i % (C1*16), c = r >> 4, d = r & 15;
    W1t[(size_t)(k*16 + d)*C1 + c] = W1[i];
}

// ---- per-voxel compacted neighbor list: list[n][t] = (k<<16)|idx, cnt[n] ----
__global__ void k_nbr(const int* __restrict__ coors, const unsigned short* __restrict__ grid,
                      int* __restrict__ list, int* __restrict__ cnt) {
    int n = blockIdx.x * blockDim.x + threadIdx.x;
    if (n >= NVOX) return;
    int b = coors[4*n+0], z = coors[4*n+1], y = coors[4*n+2], x = coors[4*n+3];
    int c = 0;
    int* lp = list + n * 27;
    #pragma unroll
    for (int dz = 0; dz < 3; ++dz) {
        #pragma unroll
        for (int dy = 0; dy < 3; ++dy) {
            const unsigned short* row = grid + ((size_t)(b*PD + z + dz)*PH + (y + dy))*PW + x;
            #pragma unroll
            for (int dx = 0; dx < 3; ++dx) {
                int id = (int)row[dx] - 1;
                if (id >= 0) lp[c++] = ((dz*9 + dy*3 + dx) << 16) | id;
            }
        }
    }
    cnt[n] = c;
}

// ---- subm conv 1: 128 -> 16, ReLU. One wave per voxel, all-float4 loads ----
// lane = q*16 + d : q = c-quarter (32 channels), d = output channel.
__global__ void k_subm1(const float* __restrict__ feat,
                        const float* __restrict__ W1t,
                        const int* __restrict__ list, const int* __restrict__ cnt,
                        float* __restrict__ x1) {
    int wid = (blockIdx.x * blockDim.x + threadIdx.x) >> 6;   // wave id = voxel
    int lane = threadIdx.x & 63;
    if (wid >= NVOX) return;
    int d = lane & 15, q = lane >> 4;
    int m = cnt[wid];                       // wave-uniform
    const int* lp = list + wid * 27;
    float a0 = 0.f, a1 = 0.f, a2 = 0.f, a3 = 0.f;
    for (int t = 0; t < m; ++t) {
        int e = lp[t];                      // broadcast load
        int k = e >> 16, idx = e & 0xFFFF;
        const float4* f4 = (const float4*)(feat + (size_t)idx * C1) + q*8;
        const float4* w4 = (const float4*)(W1t + (size_t)(k*16 + d)*C1) + q*8;
        #pragma unroll
        for (int j = 0; j < 8; ++j) {
            float4 fv = f4[j], wv = w4[j];
            a0 += fv.x * wv.x;
            a1 += fv.y * wv.y;
            a2 += fv.z * wv.z;
            a3 += fv.w * wv.w;
        }
    }
    float r = (a0 + a1) + (a2 + a3);
    r += __shfl_xor(r, 16);
    r += __shfl_xor(r, 32);
    if (lane < 16) x1[wid*16 + d] = fmaxf(r, 0.f);
}

// ---- subm conv 2: 16 -> 16, ReLU. W2 in LDS; only valid taps ----
__global__ void k_subm2(const float* __restrict__ x1,
                        const float* __restrict__ W2,
                        const int* __restrict__ list, const int* __restrict__ cnt,
                        float* __restrict__ x2) {
    __shared__ int   s_list[16][28];
    __shared__ int   s_cnt[16];
    __shared__ float s_w2[27*16*16];
    for (int i = threadIdx.x; i < 27*16*16; i += 256) s_w2[i] = W2[i];
    int base = blockIdx.x * 16;
    if (threadIdx.x < 16) {
        int n = base + threadIdx.x;
        s_cnt[threadIdx.x] = (n < NVOX) ? cnt[n] : 0;
    }
    for (int i = threadIdx.x; i < 16*27; i += 256) {
        int v = i / 27, k = i % 27;
        int n = base + v;
        s_list[v][k] = (n < NVOX) ? list[n*27 + k] : 0;
    }
    __syncthreads();
    int v = threadIdx.x >> 4, d = threadIdx.x & 15;
    int n = base + v;
    if (n >= NVOX) return;
    int m = s_cnt[v];
    float a0 = 0.f, a1 = 0.f, a2 = 0.f, a3 = 0.f;
    for (int t = 0; t < m; ++t) {
        int e = s_list[v][t];
        int k = e >> 16, idx = e & 0xFFFF;
        const float4* x4 = (const float4*)(x1 + (size_t)idx * 16);
        float4 xa = x4[0], xb = x4[1], xc = x4[2], xd = x4[3];
        const float* wp = s_w2 + k * 256 + d;
        a0 += xa.x * wp[0*16]  + xa.y * wp[1*16]  + xa.z * wp[2*16]  + xa.w * wp[3*16];
        a1 += xb.x * wp[4*16]  + xb.y * wp[5*16]  + xb.z * wp[6*16]  + xb.w * wp[7*16];
        a2 += xc.x * wp[8*16]  + xc.y * wp[9*16]  + xc.z * wp[10*16] + xc.w * wp[11*16];
        a3 += xd.x * wp[12*16] + xd.y * wp[13*16] + xd.z * wp[14*16] + xd.w * wp[15*16];
    }
    x2[n*16 + d] = fmaxf((a0 + a1) + (a2 + a3), 0.f);
}

// ---- valid downsample taps for one axis, from PADDED input coord ----
__device__ __forceinline__ int axis_taps(int pcoord, int outdim, int* ds, int* ps) {
    if (pcoord & 1) { ds[0] = 1; ps[0] = pcoord >> 1; return 1; }
    int h = pcoord >> 1, nu = 0;
    if (h < outdim) { ds[nu] = 0; ps[nu] = h; nu++; }
    ds[nu] = 2; ps[nu] = h - 1; nu++;
    return nu;
}

// ---- stride-2 conv 16 -> 32 as scatter + touched-flag store ----
__global__ void k_scatter(const float* __restrict__ x2,
                          const float* __restrict__ W3,
                          const int* __restrict__ coors,
                          float* __restrict__ out,
                          unsigned char* __restrict__ flag) {
    int v = threadIdx.x >> 5, d = threadIdx.x & 31;
    int n = blockIdx.x * 8 + v;
    if (n >= NVOX) return;
    int b  = coors[4*n+0];
    int zp = coors[4*n+1] + 1, yp = coors[4*n+2] + 1, xp = coors[4*n+3] + 1;
    int dz[2], pz[2], dy[2], py[2], dx[2], px[2];
    int nz = axis_taps(zp, DO_, dz, pz);
    int ny = axis_taps(yp, HO_, dy, py);
    int nx = axis_taps(xp, WO_, dx, px);
    const float4* xr = (const float4*)(x2 + (size_t)n * 16);
    float r[16];
    *(float4*)(r + 0)  = xr[0];
    *(float4*)(r + 4)  = xr[1];
    *(float4*)(r + 8)  = xr[2];
    *(float4*)(r + 12) = xr[3];
    int bofs = b * (DO_*HO_*WO_);
    for (int iz = 0; iz < nz; ++iz)
        for (int iy = 0; iy < ny; ++iy)
            for (int ix = 0; ix < nx; ++ix) {
                int k = dz[iz]*9 + dy[iy]*3 + dx[ix];
                int p = bofs + (pz[iz]*HO_ + py[iy])*WO_ + px[ix];
                const float* w = W3 + k*512 + d;   // W3[k][c][d], stride 32 over c
                float acc = 0.f;
                #pragma unroll
                for (int c = 0; c < 16; ++c) acc += r[c] * w[c * 32];
                atomicAdd(out + (size_t)p * 32 + d, acc);
                if (d == 0) flag[p] = 1;           // plain store, races benign
            }
}

// ---- dense flag-scan ReLU: touch only flagged positions ----
__global__ void k_relu_flag(const unsigned char* __restrict__ flag,
                            float* __restrict__ out) {
    int p = blockIdx.x * blockDim.x + threadIdx.x;
    if (p >= OUT_POS) return;
    if (!flag[p]) return;
    float4* o = (float4*)(out + (size_t)p * 32);
    #pragma unroll
    for (int j = 0; j < 8; ++j) {
        float4 v = o[j];
        v.x = fmaxf(v.x, 0.f); v.y = fmaxf(v.y, 0.f);
        v.z = fmaxf(v.z, 0.f); v.w = fmaxf(v.w, 0.f);
        o[j] = v;
    }
}

extern "C" void kernel_launch(void* const* d_in, const int* in_sizes, int n_in,
                              void* d_out, int out_size, void* d_ws, size_t ws_size,
                              hipStream_t stream) {
    const float* feat  = (const float*)d_in[0];  // f32 (N,128)
    const int*   coors = (const int*)d_in[1];    // int32 (N,4)
    const float* W1    = (const float*)d_in[2];  // f32 (27,128,16)
    const float* W2    = (const float*)d_in[3];  // f32 (27,16,16)
    const float* W3    = (const float*)d_in[4];  // f32 (27,16,32)
    float* out = (float*)d_out;                  // f32 (2,21,200,176,32)

    char* ws = (char*)d_ws;
    size_t off = 0;
    unsigned short* grid = (unsigned short*)(ws + off);
    off += (((size_t)GRID_CELLS*2) + 255) & ~(size_t)255;
    int* list = (int*)(ws + off); off += (((size_t)NVOX*27*4) + 255) & ~(size_t)255;
    int* cnt  = (int*)(ws + off); off += (((size_t)NVOX*4)    + 255) & ~(size_t)255;
    float* x1 = (float*)(ws + off); off += (((size_t)NVOX*16*4) + 255) & ~(size_t)255;
    float* x2 = (float*)(ws + off); off += (((size_t)NVOX*16*4) + 255) & ~(size_t)255;
    float* W1t = (float*)(ws + off); off += (((size_t)27*C1*16*4) + 255) & ~(size_t)255;
    unsigned char* flag = (unsigned char*)(ws + off); off += ((size_t)OUT_POS + 255) & ~(size_t)255;

    hipMemsetAsync(grid, 0x00, (size_t)GRID_CELLS * 2, stream);   // grid = 0 (empty)
    hipMemsetAsync(flag, 0x00, (size_t)OUT_POS, stream);
    hipMemsetAsync(out, 0x00, OUT_BYTES, stream);
    k_build<<<(NVOX + 255) / 256, 256, 0, stream>>>(coors, grid);
    k_wtrans<<<(27*C1*16 + 255) / 256, 256, 0, stream>>>(W1, W1t);
    k_nbr<<<(NVOX + 255) / 256, 256, 0, stream>>>(coors, grid, list, cnt);
    k_subm1<<<(NVOX*64 + 255) / 256, 256, 0, stream>>>(feat, W1t, list, cnt, x1);
    k_subm2<<<(NVOX + 15) / 16, 256, 0, stream>>>(x1, W2, list, cnt, x2);
    k_scatter<<<(NVOX + 7) / 8, 256, 0, stream>>>(x2, W3, coors, out, flag);
    k_relu_flag<<<(OUT_POS + 255) / 256, 256, 0, stream>>>(flag, out);
}